// Round 7
// baseline (712.679 us; speedup 1.0000x reference)
//
#include <hip/hip_runtime.h>

#define HD 64
#define TT 512
#define BB 256
#define NROWS (BB * TT)  // 131072

typedef __attribute__((ext_vector_type(8))) short short8_t;
typedef __attribute__((ext_vector_type(4))) float f32x4;

// ---------- helpers ----------
__device__ __forceinline__ float rl(float v, int k) {
  return __uint_as_float(__builtin_amdgcn_readlane(__float_as_uint(v), k));
}
__device__ __forceinline__ float wsum(float v) {
#pragma unroll
  for (int m = 32; m >= 1; m >>= 1) v += __shfl_xor(v, m, 64);
  return v;
}
__device__ __forceinline__ float sigmoidf_(float x) {
  return 1.0f / (1.0f + __expf(-x));
}
__device__ __forceinline__ float tanhf_(float x) {
  return 1.0f - 2.0f / (__expf(2.0f * x) + 1.0f);
}
__device__ __forceinline__ unsigned short f2bf(float f) {
  unsigned int u = __float_as_uint(f);
  u = (u + 0x7fffu + ((u >> 16) & 1u)) >> 16;
  return (unsigned short)u;
}
__device__ __forceinline__ float ldz(const float* p) { return *p; }
__device__ __forceinline__ float ldz(const unsigned short* p) {
  return __uint_as_float(((unsigned int)(*p)) << 16);
}
__device__ __forceinline__ void store8(float* p, float4 a, float4 b) {
  *(float4*)p = a;
  *(float4*)(p + 4) = b;
}
__device__ __forceinline__ void store8(unsigned short* p, float4 a, float4 b) {
  union { unsigned short us[8]; int4 v; } u;
  u.us[0] = f2bf(a.x); u.us[1] = f2bf(a.y); u.us[2] = f2bf(a.z); u.us[3] = f2bf(a.w);
  u.us[4] = f2bf(b.x); u.us[5] = f2bf(b.y); u.us[6] = f2bf(b.z); u.us[7] = f2bf(b.w);
  *(int4*)p = u.v;
}
__device__ __forceinline__ float4 fma4(float4 a, float s, float4 w) {
  a.x += s * w.x; a.y += s * w.y; a.z += s * w.z; a.w += s * w.w;
  return a;
}
__device__ __forceinline__ float4 add4(float4 a, float4 b) {
  a.x += b.x; a.y += b.y; a.z += b.z; a.w += b.w;
  return a;
}

// ---------- Kernel A: xy = [LN(action@W_act+b_act), relu(...)]; Zx = xy @ W_lstm[0:128] + b_lstm ----------
template <typename ZT>
__global__ __launch_bounds__(256) void kA(const float* __restrict__ act,
                                          const float* __restrict__ Wact,
                                          const float* __restrict__ bact,
                                          const float* __restrict__ g2,
                                          const float* __restrict__ beta2,
                                          const float* __restrict__ Wl,
                                          const float* __restrict__ bl,
                                          ZT* __restrict__ Zx) {
  __shared__ float xy[64][128];
  const int tid = threadIdx.x;
  const int lane = tid & 63;
  const int wv = tid >> 6;
  const int r0blk = blockIdx.x * 64;

  float wreg[64];
#pragma unroll
  for (int k = 0; k < 64; ++k) wreg[k] = Wact[k * 64 + lane];
  const float ba = bact[lane], gg = g2[lane], bb = beta2[lane];

  for (int i = 0; i < 16; ++i) {
    const int r = i * 4 + wv;
    const int row = r0blk + r;
    const float a = act[row * 64 + lane];
    float yd = ba;
#pragma unroll
    for (int k = 0; k < 64; ++k) yd += rl(a, k) * wreg[k];
    const float mu = wsum(yd) * (1.0f / 64.0f);
    const float d = yd - mu;
    const float var = wsum(d * d) * (1.0f / 64.0f);
    const float x = d * rsqrtf(var + 1e-12f) * gg + bb;
    xy[r][lane] = x;
    xy[r][64 + lane] = fmaxf(yd, 0.0f);
  }
  __syncthreads();

  const int tc = tid & 31;
  const int tr = tid >> 5;
  const int c0 = tc * 8;
  float4 accA[8], accB[8];
#pragma unroll
  for (int r = 0; r < 8; ++r) {
    accA[r] = make_float4(0.f, 0.f, 0.f, 0.f);
    accB[r] = make_float4(0.f, 0.f, 0.f, 0.f);
  }
  for (int kk = 0; kk < 128; kk += 4) {
    float4 xv[8];
#pragma unroll
    for (int r = 0; r < 8; ++r) xv[r] = *(const float4*)&xy[tr * 8 + r][kk];
#pragma unroll
    for (int dk = 0; dk < 4; ++dk) {
      const float4 wa = *(const float4*)&Wl[(kk + dk) * 256 + c0];
      const float4 wb = *(const float4*)&Wl[(kk + dk) * 256 + c0 + 4];
#pragma unroll
      for (int r = 0; r < 8; ++r) {
        const float xr = (dk == 0) ? xv[r].x : (dk == 1) ? xv[r].y : (dk == 2) ? xv[r].z : xv[r].w;
        accA[r] = fma4(accA[r], xr, wa);
        accB[r] = fma4(accB[r], xr, wb);
      }
    }
  }
  const float4 bla = *(const float4*)&bl[c0];
  const float4 blb = *(const float4*)&bl[c0 + 4];
#pragma unroll
  for (int r = 0; r < 8; ++r) {
    const int row = r0blk + tr * 8 + r;
    store8(&Zx[(size_t)row * 256 + c0], add4(accA[r], bla), add4(accB[r], blb));
  }
}

// ---------- Kernel B v6: 16 batches/block, 4 waves, MFMA with batch-rows, Zx as C-operand ----------
// Wave w owns gate-cols m in [16w,16w+16) for all 4 gates: 8 MFMAs/step, 32 VGPR weights.
// Lane l (bq=l>>4, cl=l&15) owns (batch bq*4+r, m=16w+cl) for r=0..3.
template <typename ZT>
__global__ __launch_bounds__(256, 1) void kB6(const ZT* __restrict__ Zx,
                                              const float* __restrict__ Wl,
                                              const float* __restrict__ c0p,
                                              const float* __restrict__ h0p,
                                              float* __restrict__ hs,
                                              float* __restrict__ cfin,
                                              float* __restrict__ hfin) {
  __shared__ __align__(16) unsigned short h_lds[2][16][72];  // [buf][batch][m], +8 pad
  const int tid = threadIdx.x;
  const int w = tid >> 6;
  const int l = tid & 63;
  const int bq = l >> 4;
  const int cl = l & 15;
  const int m = w * 16 + cl;
  const int B0 = blockIdx.x * 16;

  // Resident B-fragments: wf[gate][khalf]; lane holds B[k][n], n=cl, k=q*32+bq*8+j
  short8_t wf[4][2];
#pragma unroll
  for (int g = 0; g < 4; ++g)
#pragma unroll
    for (int q = 0; q < 2; ++q) {
      short8_t v;
#pragma unroll
      for (int j = 0; j < 8; ++j)
        v[j] = (short)f2bf(Wl[(128 + q * 32 + bq * 8 + j) * 256 + g * 64 + w * 16 + cl]);
      wf[g][q] = v;
    }

  float c[4], hl[4];
  size_t zoff[4], hsb[4];
#pragma unroll
  for (int r = 0; r < 4; ++r) {
    const int bl = bq * 4 + r;
    const int bg = B0 + bl;
    c[r] = c0p[bg * 64 + m];
    hl[r] = h0p[bg * 64 + m];
    h_lds[0][bl][m] = f2bf(hl[r]);
    zoff[r] = (size_t)bg * TT * 256 + (size_t)(w * 16 + cl);
    hsb[r] = (size_t)bg * TT * 64 + (size_t)m;
  }
  __syncthreads();

  f32x4 P[4][4];  // [prefetch-set][gate], component = r (batch row)
#define PF(S, T)                                                          \
  _Pragma("unroll") for (int g = 0; g < 4; ++g)                           \
  _Pragma("unroll") for (int r = 0; r < 4; ++r)                           \
      P[S][g][r] = ldz(&Zx[zoff[r] + (size_t)(T) * 256 + g * 64]);

  PF(0, 0) PF(1, 1) PF(2, 2) PF(3, 3)

#define STEP(S, T)                                                                          \
  {                                                                                         \
    const short8_t a0 = *(const short8_t*)&h_lds[(T) & 1][cl][bq * 8];                      \
    const short8_t a1 = *(const short8_t*)&h_lds[(T) & 1][cl][32 + bq * 8];                 \
    f32x4 acc[4];                                                                           \
    _Pragma("unroll") for (int g = 0; g < 4; ++g) {                                         \
      f32x4 t0 = __builtin_amdgcn_mfma_f32_16x16x32_bf16(a0, wf[g][0], P[S][g], 0, 0, 0);   \
      acc[g] = __builtin_amdgcn_mfma_f32_16x16x32_bf16(a1, wf[g][1], t0, 0, 0, 0);          \
    }                                                                                       \
    int tn = (T) + 4;                                                                       \
    if (tn > TT - 1) tn = TT - 1;                                                           \
    PF(S, tn)                                                                               \
    _Pragma("unroll") for (int r = 0; r < 4; ++r) {                                         \
      const float zi = acc[0][r], zj = acc[1][r], zf = acc[2][r], zo = acc[3][r];           \
      c[r] = c[r] * sigmoidf_(zf + 1.0f) + sigmoidf_(zi) * tanhf_(zj);                      \
      hl[r] = sigmoidf_(zo) * tanhf_(c[r]);                                                 \
      hs[hsb[r] + (size_t)(T) * 64] = hl[r];                                                \
      h_lds[((T) + 1) & 1][bq * 4 + r][m] = f2bf(hl[r]);                                    \
    }                                                                                       \
    __syncthreads();                                                                        \
  }

#pragma unroll 1
  for (int t = 0; t < TT; t += 4) {
    STEP(0, t)
    STEP(1, t + 1)
    STEP(2, t + 2)
    STEP(3, t + 3)
  }
#undef STEP
#undef PF

#pragma unroll
  for (int r = 0; r < 4; ++r) {
    const int bg = B0 + bq * 4 + r;
    cfin[bg * 64 + m] = c[r];
    hfin[bg * 64 + m] = hl[r];
  }
}

// ---------- Kernel C: out = LN(hs) ; q = out @ W_out + b_out ----------
__global__ __launch_bounds__(256) void kC(const float* __restrict__ hs,
                                          const float* __restrict__ g3,
                                          const float* __restrict__ beta3,
                                          const float* __restrict__ Wout,
                                          const float* __restrict__ bout,
                                          float* __restrict__ q) {
  const int lane = threadIdx.x & 63;
  const int wv = threadIdx.x >> 6;
  const float g = g3[lane], be = beta3[lane], wo = Wout[lane], bo = bout[0];
  for (int n = blockIdx.x * 4 + wv; n < NROWS; n += gridDim.x * 4) {
    const float v = hs[(size_t)n * 64 + lane];
    const float mu = wsum(v) * (1.0f / 64.0f);
    const float d = v - mu;
    const float var = wsum(d * d) * (1.0f / 64.0f);
    const float xn = d * rsqrtf(var + 1e-12f) * g + be;
    const float s = wsum(xn * wo);
    if (lane == 0) q[n] = s + bo;
  }
}

// ---------- launch ----------
extern "C" void kernel_launch(void* const* d_in, const int* in_sizes, int n_in,
                              void* d_out, int out_size, void* d_ws, size_t ws_size,
                              hipStream_t stream) {
  const float* action = (const float*)d_in[1];
  const float* c0 = (const float*)d_in[2];
  const float* h0 = (const float*)d_in[3];
  const float* Wact = (const float*)d_in[8];
  const float* bact = (const float*)d_in[9];
  const float* g2 = (const float*)d_in[10];
  const float* b2 = (const float*)d_in[11];
  const float* Wl = (const float*)d_in[12];
  const float* bl = (const float*)d_in[13];
  const float* g3 = (const float*)d_in[14];
  const float* b3 = (const float*)d_in[15];
  const float* Wout = (const float*)d_in[16];
  const float* bout = (const float*)d_in[17];

  float* q = (float*)d_out;
  float* cfin = q + NROWS;
  float* hfin = cfin + BB * HD;

  const size_t zx32 = (size_t)NROWS * 256 * sizeof(float);
  const size_t zx16 = (size_t)NROWS * 256 * sizeof(unsigned short);
  const size_t hsb = (size_t)NROWS * 64 * sizeof(float);

  if (ws_size >= zx32 + hsb) {
    float* Zx = (float*)d_ws;
    float* hs = (float*)((char*)d_ws + zx32);
    kA<float><<<NROWS / 64, 256, 0, stream>>>(action, Wact, bact, g2, b2, Wl, bl, Zx);
    kB6<float><<<BB / 16, 256, 0, stream>>>(Zx, Wl, c0, h0, hs, cfin, hfin);
    kC<<<2048, 256, 0, stream>>>(hs, g3, b3, Wout, bout, q);
  } else {
    unsigned short* Zx = (unsigned short*)d_ws;
    float* hs = (float*)((char*)d_ws + zx16);
    kA<unsigned short><<<NROWS / 64, 256, 0, stream>>>(action, Wact, bact, g2, b2, Wl, bl, Zx);
    kB6<unsigned short><<<BB / 16, 256, 0, stream>>>(Zx, Wl, c0, h0, hs, cfin, hfin);
    kC<<<2048, 256, 0, stream>>>(hs, g3, b3, Wout, bout, q);
  }
}

// Round 8
// 492.606 us; speedup vs baseline: 1.4468x; 1.4468x over previous
//
#include <hip/hip_runtime.h>

#define HD 64
#define TT 512
#define BB 256
#define NROWS (BB * TT)  // 131072

typedef __attribute__((ext_vector_type(8))) short short8_t;
typedef __attribute__((ext_vector_type(4))) float f32x4;

// ---------- helpers ----------
__device__ __forceinline__ float rl(float v, int k) {
  return __uint_as_float(__builtin_amdgcn_readlane(__float_as_uint(v), k));
}
__device__ __forceinline__ float wsum(float v) {
#pragma unroll
  for (int m = 32; m >= 1; m >>= 1) v += __shfl_xor(v, m, 64);
  return v;
}
__device__ __forceinline__ float sigmoidf_(float x) {
  return 1.0f / (1.0f + __expf(-x));
}
__device__ __forceinline__ float tanhf_(float x) {
  return 1.0f - 2.0f / (__expf(2.0f * x) + 1.0f);
}
__device__ __forceinline__ unsigned short f2bf(float f) {
  unsigned int u = __float_as_uint(f);
  u = (u + 0x7fffu + ((u >> 16) & 1u)) >> 16;
  return (unsigned short)u;
}
__device__ __forceinline__ float ldz(const float* p) { return *p; }
__device__ __forceinline__ float ldz(const unsigned short* p) {
  return __uint_as_float(((unsigned int)(*p)) << 16);
}
__device__ __forceinline__ void store8(float* p, float4 a, float4 b) {
  *(float4*)p = a;
  *(float4*)(p + 4) = b;
}
__device__ __forceinline__ void store8(unsigned short* p, float4 a, float4 b) {
  union { unsigned short us[8]; int4 v; } u;
  u.us[0] = f2bf(a.x); u.us[1] = f2bf(a.y); u.us[2] = f2bf(a.z); u.us[3] = f2bf(a.w);
  u.us[4] = f2bf(b.x); u.us[5] = f2bf(b.y); u.us[6] = f2bf(b.z); u.us[7] = f2bf(b.w);
  *(int4*)p = u.v;
}
__device__ __forceinline__ float4 fma4(float4 a, float s, float4 w) {
  a.x += s * w.x; a.y += s * w.y; a.z += s * w.z; a.w += s * w.w;
  return a;
}
__device__ __forceinline__ float4 add4(float4 a, float4 b) {
  a.x += b.x; a.y += b.y; a.z += b.z; a.w += b.w;
  return a;
}

// ---------- Kernel A: xy = [LN(action@W_act+b_act), relu(...)]; Zx = xy @ W_lstm[0:128] + b_lstm ----------
template <typename ZT>
__global__ __launch_bounds__(256) void kA(const float* __restrict__ act,
                                          const float* __restrict__ Wact,
                                          const float* __restrict__ bact,
                                          const float* __restrict__ g2,
                                          const float* __restrict__ beta2,
                                          const float* __restrict__ Wl,
                                          const float* __restrict__ bl,
                                          ZT* __restrict__ Zx) {
  __shared__ float xy[64][128];
  const int tid = threadIdx.x;
  const int lane = tid & 63;
  const int wv = tid >> 6;
  const int r0blk = blockIdx.x * 64;

  float wreg[64];
#pragma unroll
  for (int k = 0; k < 64; ++k) wreg[k] = Wact[k * 64 + lane];
  const float ba = bact[lane], gg = g2[lane], bb = beta2[lane];

  for (int i = 0; i < 16; ++i) {
    const int r = i * 4 + wv;
    const int row = r0blk + r;
    const float a = act[row * 64 + lane];
    float yd = ba;
#pragma unroll
    for (int k = 0; k < 64; ++k) yd += rl(a, k) * wreg[k];
    const float mu = wsum(yd) * (1.0f / 64.0f);
    const float d = yd - mu;
    const float var = wsum(d * d) * (1.0f / 64.0f);
    const float x = d * rsqrtf(var + 1e-12f) * gg + bb;
    xy[r][lane] = x;
    xy[r][64 + lane] = fmaxf(yd, 0.0f);
  }
  __syncthreads();

  const int tc = tid & 31;
  const int tr = tid >> 5;
  const int c0 = tc * 8;
  float4 accA[8], accB[8];
#pragma unroll
  for (int r = 0; r < 8; ++r) {
    accA[r] = make_float4(0.f, 0.f, 0.f, 0.f);
    accB[r] = make_float4(0.f, 0.f, 0.f, 0.f);
  }
  for (int kk = 0; kk < 128; kk += 4) {
    float4 xv[8];
#pragma unroll
    for (int r = 0; r < 8; ++r) xv[r] = *(const float4*)&xy[tr * 8 + r][kk];
#pragma unroll
    for (int dk = 0; dk < 4; ++dk) {
      const float4 wa = *(const float4*)&Wl[(kk + dk) * 256 + c0];
      const float4 wb = *(const float4*)&Wl[(kk + dk) * 256 + c0 + 4];
#pragma unroll
      for (int r = 0; r < 8; ++r) {
        const float xr = (dk == 0) ? xv[r].x : (dk == 1) ? xv[r].y : (dk == 2) ? xv[r].z : xv[r].w;
        accA[r] = fma4(accA[r], xr, wa);
        accB[r] = fma4(accB[r], xr, wb);
      }
    }
  }
  const float4 bla = *(const float4*)&bl[c0];
  const float4 blb = *(const float4*)&bl[c0 + 4];
#pragma unroll
  for (int r = 0; r < 8; ++r) {
    const int row = r0blk + tr * 8 + r;
    store8(&Zx[(size_t)row * 256 + c0], add4(accA[r], bla), add4(accB[r], blb));
  }
}

// ---------- Kernel B v7: one wave per batch, MFMA h@Wh, waves_per_eu(1,1) to force W residency ----------
template <typename ZT>
__global__ __launch_bounds__(64) __attribute__((amdgpu_waves_per_eu(1, 1)))
void kB7(const ZT* __restrict__ Zx,
         const float* __restrict__ Wl,
         const float* __restrict__ c0p,
         const float* __restrict__ h0p,
         float* __restrict__ hs,
         float* __restrict__ cfin,
         float* __restrict__ hfin) {
  __shared__ __align__(16) unsigned short h_lds[64];
  const int l = threadIdx.x;
  const int b = blockIdx.x;
  const int grp = l >> 4;   // 0..3
  const int col = l & 15;

  // W_h as bf16 B-fragments: tile t16 = cols [16*t16,16*t16+16);
  // lane l holds B[k][n]: n=col, k=32q+grp*8+j for k-half q. 32 frags x 4 VGPR = 128 VGPRs.
  short8_t wf0[16], wf1[16];
#pragma unroll
  for (int t16 = 0; t16 < 16; ++t16) {
    short8_t w0, w1;
#pragma unroll
    for (int j = 0; j < 8; ++j) {
      w0[j] = (short)f2bf(Wl[(128 + 0 + grp * 8 + j) * 256 + 16 * t16 + col]);
      w1[j] = (short)f2bf(Wl[(128 + 32 + grp * 8 + j) * 256 + 16 * t16 + col]);
    }
    wf0[t16] = w0;
    wf1[t16] = w1;
  }

  const f32x4 zc = {0.f, 0.f, 0.f, 0.f};

  float c = c0p[b * 64 + l];
  float h = h0p[b * 64 + l];

  const ZT* zrow = Zx + (size_t)b * TT * 256;
  float* hsrow = hs + (size_t)b * TT * 64;

#define LD4(PI, PJ, PF, PO, T)                       \
  PI = ldz(&zrow[(size_t)(T) * 256 + 0 + l]);        \
  PJ = ldz(&zrow[(size_t)(T) * 256 + 64 + l]);       \
  PF = ldz(&zrow[(size_t)(T) * 256 + 128 + l]);      \
  PO = ldz(&zrow[(size_t)(T) * 256 + 192 + l]);

  float pAi, pAj, pAf, pAo, pBi, pBj, pBf, pBo;
  float pCi, pCj, pCf, pCo, pDi, pDj, pDf, pDo;
  LD4(pAi, pAj, pAf, pAo, 0)
  LD4(pBi, pBj, pBf, pBo, 1)
  LD4(pCi, pCj, pCf, pCo, 2)
  LD4(pDi, pDj, pDf, pDo, 3)

#define STEP(PI, PJ, PF, PO, T)                                               \
  {                                                                           \
    h_lds[l] = f2bf(h);                                                       \
    /* same-wave DS ops are FIFO-ordered; compiler inserts lgkmcnt */         \
    const short8_t a0 = *(const short8_t*)&h_lds[grp * 8];                    \
    const short8_t a1 = *(const short8_t*)&h_lds[32 + grp * 8];               \
    f32x4 acc[16];                                                            \
    _Pragma("unroll") for (int t16 = 0; t16 < 16; ++t16) {                    \
      f32x4 tmp = __builtin_amdgcn_mfma_f32_16x16x32_bf16(a0, wf0[t16], zc, 0, 0, 0); \
      acc[t16] = __builtin_amdgcn_mfma_f32_16x16x32_bf16(a1, wf1[t16], tmp, 0, 0, 0); \
    }                                                                         \
    const float zi = (grp == 0 ? acc[0].x : grp == 1 ? acc[1].x : grp == 2 ? acc[2].x : acc[3].x) + PI;   \
    const float zj = (grp == 0 ? acc[4].x : grp == 1 ? acc[5].x : grp == 2 ? acc[6].x : acc[7].x) + PJ;   \
    const float zf = (grp == 0 ? acc[8].x : grp == 1 ? acc[9].x : grp == 2 ? acc[10].x : acc[11].x) + PF; \
    const float zo = (grp == 0 ? acc[12].x : grp == 1 ? acc[13].x : grp == 2 ? acc[14].x : acc[15].x) + PO; \
    int tn = (T) + 4;                                                         \
    if (tn > TT - 1) tn = TT - 1;                                             \
    LD4(PI, PJ, PF, PO, tn)                                                   \
    c = c * sigmoidf_(zf + 1.0f) + sigmoidf_(zi) * tanhf_(zj);                \
    h = sigmoidf_(zo) * tanhf_(c);                                            \
    hsrow[(size_t)(T) * 64 + l] = h;                                          \
  }

#pragma unroll 1
  for (int t = 0; t < TT; t += 4) {
    STEP(pAi, pAj, pAf, pAo, t)
    STEP(pBi, pBj, pBf, pBo, t + 1)
    STEP(pCi, pCj, pCf, pCo, t + 2)
    STEP(pDi, pDj, pDf, pDo, t + 3)
  }
#undef STEP
#undef LD4

  cfin[b * 64 + l] = c;
  hfin[b * 64 + l] = h;
}

// ---------- Kernel C: out = LN(hs) ; q = out @ W_out + b_out ----------
__global__ __launch_bounds__(256) void kC(const float* __restrict__ hs,
                                          const float* __restrict__ g3,
                                          const float* __restrict__ beta3,
                                          const float* __restrict__ Wout,
                                          const float* __restrict__ bout,
                                          float* __restrict__ q) {
  const int lane = threadIdx.x & 63;
  const int wv = threadIdx.x >> 6;
  const float g = g3[lane], be = beta3[lane], wo = Wout[lane], bo = bout[0];
  for (int n = blockIdx.x * 4 + wv; n < NROWS; n += gridDim.x * 4) {
    const float v = hs[(size_t)n * 64 + lane];
    const float mu = wsum(v) * (1.0f / 64.0f);
    const float d = v - mu;
    const float var = wsum(d * d) * (1.0f / 64.0f);
    const float xn = d * rsqrtf(var + 1e-12f) * g + be;
    const float s = wsum(xn * wo);
    if (lane == 0) q[n] = s + bo;
  }
}

// ---------- launch ----------
extern "C" void kernel_launch(void* const* d_in, const int* in_sizes, int n_in,
                              void* d_out, int out_size, void* d_ws, size_t ws_size,
                              hipStream_t stream) {
  const float* action = (const float*)d_in[1];
  const float* c0 = (const float*)d_in[2];
  const float* h0 = (const float*)d_in[3];
  const float* Wact = (const float*)d_in[8];
  const float* bact = (const float*)d_in[9];
  const float* g2 = (const float*)d_in[10];
  const float* b2 = (const float*)d_in[11];
  const float* Wl = (const float*)d_in[12];
  const float* bl = (const float*)d_in[13];
  const float* g3 = (const float*)d_in[14];
  const float* b3 = (const float*)d_in[15];
  const float* Wout = (const float*)d_in[16];
  const float* bout = (const float*)d_in[17];

  float* q = (float*)d_out;
  float* cfin = q + NROWS;
  float* hfin = cfin + BB * HD;

  const size_t zx32 = (size_t)NROWS * 256 * sizeof(float);
  const size_t zx16 = (size_t)NROWS * 256 * sizeof(unsigned short);
  const size_t hsb = (size_t)NROWS * 64 * sizeof(float);

  if (ws_size >= zx32 + hsb) {
    float* Zx = (float*)d_ws;
    float* hs = (float*)((char*)d_ws + zx32);
    kA<float><<<NROWS / 64, 256, 0, stream>>>(action, Wact, bact, g2, b2, Wl, bl, Zx);
    kB7<float><<<BB, 64, 0, stream>>>(Zx, Wl, c0, h0, hs, cfin, hfin);
    kC<<<2048, 256, 0, stream>>>(hs, g3, b3, Wout, bout, q);
  } else {
    unsigned short* Zx = (unsigned short*)d_ws;
    float* hs = (float*)((char*)d_ws + zx16);
    kA<unsigned short><<<NROWS / 64, 256, 0, stream>>>(action, Wact, bact, g2, b2, Wl, bl, Zx);
    kB7<unsigned short><<<BB, 64, 0, stream>>>(Zx, Wl, c0, h0, hs, cfin, hfin);
    kC<<<2048, 256, 0, stream>>>(hs, g3, b3, Wout, bout, q);
  }
}

// Round 9
// 464.104 us; speedup vs baseline: 1.5356x; 1.0614x over previous
//
#include <hip/hip_runtime.h>

#define HD 64
#define TT 512
#define BB 256
#define NROWS (BB * TT)  // 131072

typedef _Float16 half2_t __attribute__((ext_vector_type(2)));
typedef __attribute__((ext_vector_type(4))) float f32x4;

// ---------- helpers ----------
__device__ __forceinline__ float rl(float v, int k) {
  return __uint_as_float(__builtin_amdgcn_readlane(__float_as_uint(v), k));
}
__device__ __forceinline__ float wsum(float v) {
#pragma unroll
  for (int m = 32; m >= 1; m >>= 1) v += __shfl_xor(v, m, 64);
  return v;
}
__device__ __forceinline__ float sigmoidf_(float x) {
  return 1.0f / (1.0f + __expf(-x));
}
__device__ __forceinline__ float tanhf_(float x) {
  return 1.0f - 2.0f / (__expf(2.0f * x) + 1.0f);
}
__device__ __forceinline__ unsigned short f2bf(float f) {
  unsigned int u = __float_as_uint(f);
  u = (u + 0x7fffu + ((u >> 16) & 1u)) >> 16;
  return (unsigned short)u;
}
__device__ __forceinline__ float ldz(const float* p) { return *p; }
__device__ __forceinline__ float ldz(const unsigned short* p) {
  return __uint_as_float(((unsigned int)(*p)) << 16);
}
__device__ __forceinline__ void store8(float* p, float4 a, float4 b) {
  *(float4*)p = a;
  *(float4*)(p + 4) = b;
}
__device__ __forceinline__ void store8(unsigned short* p, float4 a, float4 b) {
  union { unsigned short us[8]; int4 v; } u;
  u.us[0] = f2bf(a.x); u.us[1] = f2bf(a.y); u.us[2] = f2bf(a.z); u.us[3] = f2bf(a.w);
  u.us[4] = f2bf(b.x); u.us[5] = f2bf(b.y); u.us[6] = f2bf(b.z); u.us[7] = f2bf(b.w);
  *(int4*)p = u.v;
}
__device__ __forceinline__ float4 fma4(float4 a, float s, float4 w) {
  a.x += s * w.x; a.y += s * w.y; a.z += s * w.z; a.w += s * w.w;
  return a;
}
__device__ __forceinline__ float4 add4(float4 a, float4 b) {
  a.x += b.x; a.y += b.y; a.z += b.z; a.w += b.w;
  return a;
}
// dot2: acc += a.x*b.x + a.y*b.y (f16 in, f32 accum)
__device__ __forceinline__ float dot2(half2_t a, half2_t b, float acc) {
#if __has_builtin(__builtin_amdgcn_fdot2)
  return __builtin_amdgcn_fdot2(a, b, acc, false);
#else
  return acc + (float)a.x * (float)b.x + (float)a.y * (float)b.y;
#endif
}
__device__ __forceinline__ half2_t pkrtz(float a, float b) {
  return __builtin_bit_cast(half2_t, __builtin_amdgcn_cvt_pkrtz(a, b));
}

// ---------- Kernel A ----------
template <typename ZT>
__global__ __launch_bounds__(256) void kA(const float* __restrict__ act,
                                          const float* __restrict__ Wact,
                                          const float* __restrict__ bact,
                                          const float* __restrict__ g2,
                                          const float* __restrict__ beta2,
                                          const float* __restrict__ Wl,
                                          const float* __restrict__ bl,
                                          ZT* __restrict__ Zx) {
  __shared__ float xy[64][128];
  const int tid = threadIdx.x;
  const int lane = tid & 63;
  const int wv = tid >> 6;
  const int r0blk = blockIdx.x * 64;

  float wreg[64];
#pragma unroll
  for (int k = 0; k < 64; ++k) wreg[k] = Wact[k * 64 + lane];
  const float ba = bact[lane], gg = g2[lane], bb = beta2[lane];

  for (int i = 0; i < 16; ++i) {
    const int r = i * 4 + wv;
    const int row = r0blk + r;
    const float a = act[row * 64 + lane];
    float yd = ba;
#pragma unroll
    for (int k = 0; k < 64; ++k) yd += rl(a, k) * wreg[k];
    const float mu = wsum(yd) * (1.0f / 64.0f);
    const float d = yd - mu;
    const float var = wsum(d * d) * (1.0f / 64.0f);
    const float x = d * rsqrtf(var + 1e-12f) * gg + bb;
    xy[r][lane] = x;
    xy[r][64 + lane] = fmaxf(yd, 0.0f);
  }
  __syncthreads();

  const int tc = tid & 31;
  const int tr = tid >> 5;
  const int c0 = tc * 8;
  float4 accA[8], accB[8];
#pragma unroll
  for (int r = 0; r < 8; ++r) {
    accA[r] = make_float4(0.f, 0.f, 0.f, 0.f);
    accB[r] = make_float4(0.f, 0.f, 0.f, 0.f);
  }
  for (int kk = 0; kk < 128; kk += 4) {
    float4 xv[8];
#pragma unroll
    for (int r = 0; r < 8; ++r) xv[r] = *(const float4*)&xy[tr * 8 + r][kk];
#pragma unroll
    for (int dk = 0; dk < 4; ++dk) {
      const float4 wa = *(const float4*)&Wl[(kk + dk) * 256 + c0];
      const float4 wb = *(const float4*)&Wl[(kk + dk) * 256 + c0 + 4];
#pragma unroll
      for (int r = 0; r < 8; ++r) {
        const float xr = (dk == 0) ? xv[r].x : (dk == 1) ? xv[r].y : (dk == 2) ? xv[r].z : xv[r].w;
        accA[r] = fma4(accA[r], xr, wa);
        accB[r] = fma4(accB[r], xr, wb);
      }
    }
  }
  const float4 bla = *(const float4*)&bl[c0];
  const float4 blb = *(const float4*)&bl[c0 + 4];
#pragma unroll
  for (int r = 0; r < 8; ++r) {
    const int row = r0blk + tr * 8 + r;
    store8(&Zx[(size_t)row * 256 + c0], add4(accA[r], bla), add4(accB[r], blb));
  }
}

// ---------- Kernel B v8: 4 waves k-split, lane-local gates, f16 dot2, 1 barrier/step ----------
// Wave w computes partial dots over k in [16w,16w+16) for ALL 256 gate-cols (lane l -> cols
// {l,64+l,128+l,192+l}). Partials summed via LDS; every wave then computes identical gates,
// so h[l] stays resident in lane l of every wave. No vmcnt drain at the barrier.
template <typename ZT>
__global__ __launch_bounds__(256, 1) void kB8(const ZT* __restrict__ Zx,
                                              const float* __restrict__ Wl,
                                              const float* __restrict__ c0p,
                                              const float* __restrict__ h0p,
                                              float* __restrict__ hs,
                                              float* __restrict__ cfin,
                                              float* __restrict__ hfin) {
  __shared__ float part[2][4][4][64];  // [buf][wave][gate][m] : 8 KB, conflict-free
  const int tid = threadIdx.x;
  const int w = tid >> 6;
  const int l = tid & 63;
  const int b = blockIdx.x;
  const int k0 = w * 16;

  // weights: pair p = (k0+p, k0+p+8), gate col g*64+l. 32 VGPRs.
  half2_t wp[4][8];
#pragma unroll
  for (int g = 0; g < 4; ++g)
#pragma unroll
    for (int p = 0; p < 8; ++p)
      wp[g][p] = pkrtz(Wl[(128 + k0 + p) * 256 + g * 64 + l],
                       Wl[(128 + k0 + p + 8) * 256 + g * 64 + l]);

  float c = c0p[b * 64 + l];
  float h = h0p[b * 64 + l];

  const ZT* zrow = Zx + (size_t)b * TT * 256;
  float* hsrow = hs + (size_t)b * TT * 64;

#define LD4(PI, PJ, PF, PO, T)                       \
  PI = ldz(&zrow[(size_t)(T) * 256 + 0 + l]);        \
  PJ = ldz(&zrow[(size_t)(T) * 256 + 64 + l]);       \
  PF = ldz(&zrow[(size_t)(T) * 256 + 128 + l]);      \
  PO = ldz(&zrow[(size_t)(T) * 256 + 192 + l]);

  float pAi, pAj, pAf, pAo, pBi, pBj, pBf, pBo;
  float pCi, pCj, pCf, pCo, pDi, pDj, pDf, pDo;
  LD4(pAi, pAj, pAf, pAo, 0)
  LD4(pBi, pBj, pBf, pBo, 1)
  LD4(pCi, pCj, pCf, pCo, 2)
  LD4(pDi, pDj, pDf, pDo, 3)

#define STEP(PI, PJ, PF, PO, T)                                                \
  {                                                                            \
    const float hx = __shfl_xor(h, 8, 64);                                     \
    const half2_t hp = pkrtz(h, hx);                                           \
    const unsigned int hpu = __builtin_bit_cast(unsigned int, hp);             \
    float s0 = 0.f, s1 = 0.f, s2 = 0.f, s3 = 0.f;                              \
    _Pragma("unroll") for (int p = 0; p < 8; ++p) {                            \
      const unsigned int hu = __builtin_amdgcn_readlane(hpu, k0 + p);          \
      const half2_t hb = __builtin_bit_cast(half2_t, hu);                      \
      s0 = dot2(hb, wp[0][p], s0);                                             \
      s1 = dot2(hb, wp[1][p], s1);                                             \
      s2 = dot2(hb, wp[2][p], s2);                                             \
      s3 = dot2(hb, wp[3][p], s3);                                             \
    }                                                                          \
    part[(T) & 1][w][0][l] = s0;                                               \
    part[(T) & 1][w][1][l] = s1;                                               \
    part[(T) & 1][w][2][l] = s2;                                               \
    part[(T) & 1][w][3][l] = s3;                                               \
    asm volatile("s_waitcnt lgkmcnt(0)\n\ts_barrier" ::: "memory");            \
    const float zi = PI + part[(T) & 1][0][0][l] + part[(T) & 1][1][0][l] +    \
                     part[(T) & 1][2][0][l] + part[(T) & 1][3][0][l];          \
    const float zj = PJ + part[(T) & 1][0][1][l] + part[(T) & 1][1][1][l] +    \
                     part[(T) & 1][2][1][l] + part[(T) & 1][3][1][l];          \
    const float zf = PF + part[(T) & 1][0][2][l] + part[(T) & 1][1][2][l] +    \
                     part[(T) & 1][2][2][l] + part[(T) & 1][3][2][l];          \
    const float zo = PO + part[(T) & 1][0][3][l] + part[(T) & 1][1][3][l] +    \
                     part[(T) & 1][2][3][l] + part[(T) & 1][3][3][l];          \
    int tn = (T) + 4;                                                          \
    if (tn > TT - 1) tn = TT - 1;                                              \
    LD4(PI, PJ, PF, PO, tn)                                                    \
    c = c * sigmoidf_(zf + 1.0f) + sigmoidf_(zi) * tanhf_(zj);                 \
    h = sigmoidf_(zo) * tanhf_(c);                                             \
    if (w == 0) hsrow[(size_t)(T) * 64 + l] = h;                               \
  }

#pragma unroll 1
  for (int t = 0; t < TT; t += 4) {
    STEP(pAi, pAj, pAf, pAo, t)
    STEP(pBi, pBj, pBf, pBo, t + 1)
    STEP(pCi, pCj, pCf, pCo, t + 2)
    STEP(pDi, pDj, pDf, pDo, t + 3)
  }
#undef STEP
#undef LD4

  if (w == 0) {
    cfin[b * 64 + l] = c;
    hfin[b * 64 + l] = h;
  }
}

// ---------- Kernel C ----------
__global__ __launch_bounds__(256) void kC(const float* __restrict__ hs,
                                          const float* __restrict__ g3,
                                          const float* __restrict__ beta3,
                                          const float* __restrict__ Wout,
                                          const float* __restrict__ bout,
                                          float* __restrict__ q) {
  const int lane = threadIdx.x & 63;
  const int wv = threadIdx.x >> 6;
  const float g = g3[lane], be = beta3[lane], wo = Wout[lane], bo = bout[0];
  for (int n = blockIdx.x * 4 + wv; n < NROWS; n += gridDim.x * 4) {
    const float v = hs[(size_t)n * 64 + lane];
    const float mu = wsum(v) * (1.0f / 64.0f);
    const float d = v - mu;
    const float var = wsum(d * d) * (1.0f / 64.0f);
    const float xn = d * rsqrtf(var + 1e-12f) * g + be;
    const float s = wsum(xn * wo);
    if (lane == 0) q[n] = s + bo;
  }
}

// ---------- launch ----------
extern "C" void kernel_launch(void* const* d_in, const int* in_sizes, int n_in,
                              void* d_out, int out_size, void* d_ws, size_t ws_size,
                              hipStream_t stream) {
  const float* action = (const float*)d_in[1];
  const float* c0 = (const float*)d_in[2];
  const float* h0 = (const float*)d_in[3];
  const float* Wact = (const float*)d_in[8];
  const float* bact = (const float*)d_in[9];
  const float* g2 = (const float*)d_in[10];
  const float* b2 = (const float*)d_in[11];
  const float* Wl = (const float*)d_in[12];
  const float* bl = (const float*)d_in[13];
  const float* g3 = (const float*)d_in[14];
  const float* b3 = (const float*)d_in[15];
  const float* Wout = (const float*)d_in[16];
  const float* bout = (const float*)d_in[17];

  float* q = (float*)d_out;
  float* cfin = q + NROWS;
  float* hfin = cfin + BB * HD;

  const size_t zx32 = (size_t)NROWS * 256 * sizeof(float);
  const size_t zx16 = (size_t)NROWS * 256 * sizeof(unsigned short);
  const size_t hsb = (size_t)NROWS * 64 * sizeof(float);

  if (ws_size >= zx32 + hsb) {
    float* Zx = (float*)d_ws;
    float* hs = (float*)((char*)d_ws + zx32);
    kA<float><<<NROWS / 64, 256, 0, stream>>>(action, Wact, bact, g2, b2, Wl, bl, Zx);
    kB8<float><<<BB, 256, 0, stream>>>(Zx, Wl, c0, h0, hs, cfin, hfin);
    kC<<<2048, 256, 0, stream>>>(hs, g3, b3, Wout, bout, q);
  } else {
    unsigned short* Zx = (unsigned short*)d_ws;
    float* hs = (float*)((char*)d_ws + zx16);
    kA<unsigned short><<<NROWS / 64, 256, 0, stream>>>(action, Wact, bact, g2, b2, Wl, bl, Zx);
    kB8<unsigned short><<<BB, 256, 0, stream>>>(Zx, Wl, c0, h0, hs, cfin, hfin);
    kC<<<2048, 256, 0, stream>>>(hs, g3, b3, Wout, bout, q);
  }
}